// Round 16
// baseline (205.328 us; speedup 1.0000x reference)
//
#include <hip/hip_runtime.h>
#include <cstddef>

#define DD 128
#define PART_ELEMS 4096   // elements per partition block (256 thr x 16)
#define MAXB 256          // max destination-range buckets
#define MAXW 512          // max rows per bucket (LDS counter width)
#define WT_LD 136         // padded bf16 leading dim

typedef __attribute__((ext_vector_type(8))) short bf16x8;
typedef __attribute__((ext_vector_type(4))) float f32x4;

__device__ __forceinline__ unsigned bf16pk(float x, float y) {
    unsigned a = __float_as_uint(x);
    unsigned b = __float_as_uint(y);
    a = (a + 0x7FFFu + ((a >> 16) & 1u)) >> 16;
    b = (b + 0x7FFFu + ((b >> 16) & 1u)) >> 16;
    return a | (b << 16);
}
__device__ __forceinline__ unsigned short bf16r(float x) {
    unsigned u = __float_as_uint(x);
    return (unsigned short)((u + 0x7FFFu + ((u >> 16) & 1u)) >> 16);
}
__device__ __forceinline__ float bflo(unsigned u) { return __uint_as_float(u << 16); }
__device__ __forceinline__ float bfhi(unsigned u) { return __uint_as_float(u & 0xFFFF0000u); }

// ---------------------------------------------------------------------------
// one-time: W [k][col] f32 -> Wt [col][k] bf16 (two matrices)
__global__ __launch_bounds__(256)
void conv_w_kernel(const float* __restrict__ W0, const float* __restrict__ W1,
                   unsigned short* __restrict__ Wt0, unsigned short* __restrict__ Wt1)
{
    int idx = blockIdx.x * 256 + threadIdx.x;
    int k = idx >> 7, c = idx & 127;
    Wt0[c * 128 + k] = bf16r(W0[idx]);
    Wt1[c * 128 + k] = bf16r(W1[idx]);
}

// ---------------------------------------------------------------------------
// fused partition: both sides in one pass. Delta cursors (bcur pre-zeroed).
__global__ __launch_bounds__(256)
void part2_kernel(const int* __restrict__ eidx, const int* __restrict__ vidx,
                  const float* __restrict__ vrw, const float* __restrict__ erw,
                  int* __restrict__ bcur_e, int* __restrict__ bcur_v,
                  int2* __restrict__ tmp_e, int2* __restrict__ tmp_v,
                  int M, int e_shift, int v_shift, int e_bk, int v_bk,
                  int e_cap, int v_cap)
{
    __shared__ int lcnt_e[MAXB], lbase_e[MAXB], lcnt_v[MAXB], lbase_v[MAXB];
    const int t = threadIdx.x;
    const int base = blockIdx.x * PART_ELEMS;
    const int end = min(base + PART_ELEMS, M);

    if (t < e_bk) lcnt_e[t] = 0;
    if (t < v_bk) lcnt_v[t] = 0;
    __syncthreads();
    for (int j = base + t; j < end; j += 256) {
        atomicAdd(&lcnt_e[eidx[j] >> e_shift], 1);
        atomicAdd(&lcnt_v[vidx[j] >> v_shift], 1);
    }
    __syncthreads();
    if (t < e_bk) { int c = lcnt_e[t]; lbase_e[t] = t * e_cap + (c ? atomicAdd(&bcur_e[t], c) : 0); lcnt_e[t] = 0; }
    if (t < v_bk) { int c = lcnt_v[t]; lbase_v[t] = t * v_cap + (c ? atomicAdd(&bcur_v[t], c) : 0); lcnt_v[t] = 0; }
    __syncthreads();
    for (int j = base + t; j < end; j += 256) {
        int ei = eidx[j], vi = vidx[j];
        int wqe = (int)(vrw[j] * 32767.0f + 0.5f); wqe = wqe < 32767 ? wqe : 32767;
        int wqv = (int)(erw[j] * 32767.0f + 0.5f); wqv = wqv < 32767 ? wqv : 32767;
        int be = ei >> e_shift;
        int pe = lbase_e[be] + atomicAdd(&lcnt_e[be], 1);
        tmp_e[pe] = make_int2(ei | (wqe << 17), vi);
        int bv = vi >> v_shift;
        int pv = lbase_v[bv] + atomicAdd(&lcnt_v[bv], 1);
        tmp_v[pv] = make_int2(vi | (wqv << 17), ei);
    }
}

// ---------------------------------------------------------------------------
// device bodies so fine-pass and GEMM can share one fused launch
struct FineLds { int lcnt[MAXW]; int lstart[MAXW]; int sdata[256]; int scnt[256]; int spbase; };
struct GemmLds { unsigned short At[64 * WT_LD]; };   // 17.4 KB (B from L1-resident global Wt)

__device__ __forceinline__
void fine_body(int blk, FineLds& L,
               const int2* __restrict__ tmp_e, const int* __restrict__ bcur_e,
               int e_cap, int e_shift, int En, int e_bk,
               int* __restrict__ e_start, unsigned* __restrict__ e_pack,
               const int2* __restrict__ tmp_v, const int* __restrict__ bcur_v,
               int v_cap, int v_shift, int Nn, int v_bk,
               int* __restrict__ v_start, unsigned* __restrict__ v_pack, int M)
{
    const int t = threadIdx.x;
    const int2* tmp; const int* bcur; int cap, shift, n, nb, b;
    int* start; unsigned* pack;
    if (blk < e_bk) {
        tmp = tmp_e; bcur = bcur_e; cap = e_cap; shift = e_shift; n = En; nb = e_bk;
        start = e_start; pack = e_pack; b = blk;
    } else {
        tmp = tmp_v; bcur = bcur_v; cap = v_cap; shift = v_shift; n = Nn; nb = v_bk;
        start = v_start; pack = v_pack; b = blk - e_bk;
    }

    // bcur holds per-bucket COUNTS (delta cursors)
    int cnt_t = (t < nb) ? bcur[t] : 0;
    L.scnt[t] = cnt_t;
    __syncthreads();
    int xx = cnt_t;
    for (int off = 1; off < 256; off <<= 1) {
        int y = (t >= off) ? L.scnt[t - off] : 0;
        __syncthreads();
        xx += y;
        L.scnt[t] = xx;
        __syncthreads();
    }
    if (t == b) L.spbase = xx - cnt_t;
    if (b == nb - 1 && t == 0) start[n] = M;
    __syncthreads();
    const int pbase = L.spbase;

    const int d0 = b << shift;
    const int width = min(1 << shift, n - d0);
    const int tbase = b * cap;
    const int nrec = bcur[b];

    L.lcnt[t] = 0; L.lcnt[t + 256] = 0;
    __syncthreads();
    for (int j = t; j < nrec; j += 256)
        atomicAdd(&L.lcnt[(tmp[tbase + j].x & 0x1FFFF) - d0], 1);
    __syncthreads();
    int a = L.lcnt[2 * t], bb = L.lcnt[2 * t + 1];
    int s = a + bb;
    L.sdata[t] = s;
    __syncthreads();
    int x = s;
    for (int off = 1; off < 256; off <<= 1) {
        int y = (t >= off) ? L.sdata[t - off] : 0;
        __syncthreads();
        x += y;
        L.sdata[t] = x;
        __syncthreads();
    }
    int ex = x - s;
    L.lstart[2 * t] = ex;
    L.lstart[2 * t + 1] = ex + a;
    L.lcnt[2 * t] = 0; L.lcnt[2 * t + 1] = 0;   // reuse as cursors
    __syncthreads();
    for (int i = t; i < width; i += 256)
        start[d0 + i] = pbase + L.lstart[i];
    for (int j = t; j < nrec; j += 256) {
        int2 r = tmp[tbase + j];
        int di = (r.x & 0x1FFFF) - d0;
        int pos = pbase + L.lstart[di] + atomicAdd(&L.lcnt[di], 1);
        pack[pos] = (unsigned)r.y | (((unsigned)r.x >> 17) << 17);
    }
}

// GEMM body: A staged f32->bf16 in LDS; B fragments from global Wt (L1-resident).
// V2E: relu(.)*rowwt[row]; else relu(.)*scale.
template<bool V2E>
__device__ __forceinline__
void gemm_body(int blk, GemmLds& L, const float* __restrict__ A,
               const unsigned short* __restrict__ Wtg, const float* __restrict__ bias,
               const float* __restrict__ rowwt, unsigned* __restrict__ outb,
               int nrows, float scale)
{
    const int t = threadIdx.x;
    const int row0 = blk * 64;

    {
        int r = t >> 2, q = t & 3;
        int grow = row0 + r;
        uint4 o[4];
        if (grow < nrows) {
            const float4* src = reinterpret_cast<const float4*>(A + (size_t)grow * DD + q * 32);
            #pragma unroll
            for (int i = 0; i < 4; ++i) {
                float4 f0 = src[2 * i];
                float4 f1 = src[2 * i + 1];
                o[i].x = bf16pk(f0.x, f0.y);
                o[i].y = bf16pk(f0.z, f0.w);
                o[i].z = bf16pk(f1.x, f1.y);
                o[i].w = bf16pk(f1.z, f1.w);
            }
        } else {
            #pragma unroll
            for (int i = 0; i < 4; ++i) o[i] = make_uint4(0, 0, 0, 0);
        }
        uint4* dst = reinterpret_cast<uint4*>(&L.At[r * WT_LD + q * 32]);
        #pragma unroll
        for (int i = 0; i < 4; ++i) dst[i] = o[i];
    }
    __syncthreads();

    const int w  = t >> 6;
    const int l  = t & 63;
    const int lr = l & 15;
    const int lk = (l >> 4) * 8;

    f32x4 acc[8];
    #pragma unroll
    for (int i = 0; i < 8; ++i) acc[i] = 0.0f;

    const int arow = w * 16 + lr;
    #pragma unroll
    for (int ks = 0; ks < 4; ++ks) {
        bf16x8 af = *reinterpret_cast<const bf16x8*>(&L.At[arow * WT_LD + lk + ks * 32]);
        #pragma unroll
        for (int ct = 0; ct < 8; ++ct) {
            bf16x8 bfr = *reinterpret_cast<const bf16x8*>(&Wtg[(ct * 16 + lr) * 128 + lk + ks * 32]);
            acc[ct] = __builtin_amdgcn_mfma_f32_16x16x32_bf16(af, bfr, acc[ct], 0, 0, 0);
        }
    }

    float bcol[8];
    #pragma unroll
    for (int ct = 0; ct < 8; ++ct) bcol[ct] = bias[ct * 16 + lr];
    #pragma unroll
    for (int r = 0; r < 4; ++r) {
        int rl = w * 16 + (l >> 4) * 4 + r;
        int grow = row0 + rl;
        float rw = scale;
        if (V2E) rw = (grow < nrows) ? rowwt[grow] : 0.f;
        #pragma unroll
        for (int ct = 0; ct < 8; ++ct) {
            float val = fmaxf(acc[ct][r] + bcol[ct], 0.f) * rw;
            L.At[rl * WT_LD + ct * 16 + lr] = bf16r(val);
        }
    }
    {
        int r = t >> 2, part = t & 3;
        int grow = row0 + r;
        if (grow < nrows) {
            const uint4* src = reinterpret_cast<const uint4*>(&L.At[r * WT_LD + part * 32]);
            uint4* dst = reinterpret_cast<uint4*>(outb + (size_t)grow * 64 + part * 16);
            dst[0] = src[0]; dst[1] = src[1]; dst[2] = src[2]; dst[3] = src[3];
        }
    }
}

// ---------------------------------------------------------------------------
// fused launch: blocks [0, e_bk+v_bk) do the fine pass; the rest do the v2e GEMM
__global__ __launch_bounds__(256)
void fused_fine_gemm_kernel(const int2* __restrict__ tmp_e, const int* __restrict__ bcur_e,
                            int e_cap, int e_shift, int En, int e_bk,
                            int* __restrict__ e_start, unsigned* __restrict__ e_pack,
                            const int2* __restrict__ tmp_v, const int* __restrict__ bcur_v,
                            int v_cap, int v_shift, int Nn, int v_bk,
                            int* __restrict__ v_start, unsigned* __restrict__ v_pack, int M,
                            const float* __restrict__ v, const unsigned short* __restrict__ Wt0,
                            const float* __restrict__ bv, const float* __restrict__ vweight,
                            unsigned* __restrict__ vwb)
{
    __shared__ union SM { FineLds f; GemmLds g; } sm;
    const int nfine = e_bk + v_bk;
    if ((int)blockIdx.x < nfine) {
        fine_body(blockIdx.x, sm.f, tmp_e, bcur_e, e_cap, e_shift, En, e_bk, e_start, e_pack,
                  tmp_v, bcur_v, v_cap, v_shift, Nn, v_bk, v_start, v_pack, M);
    } else {
        gemm_body<true>(blockIdx.x - nfine, sm.g, v, Wt0, bv, vweight, vwb, Nn, 1.0f);
    }
}

// standalone GEMM for the e2v side
__global__ __launch_bounds__(256)
void gemm_mfma_kernel(const float* __restrict__ A, const unsigned short* __restrict__ Wtg,
                      const float* __restrict__ bias, unsigned* __restrict__ outb,
                      int nrows, float scale)
{
    __shared__ GemmLds sm;
    gemm_body<false>(blockIdx.x, sm, A, Wtg, bias, nullptr, outb, nrows, scale);
}

// ---------------------------------------------------------------------------
// e-aggregation, quarter-wave gathers (round-12 structure, best measured):
// lane group (lane>>4) takes incidence j+qw; each lane loads uint4 (8 bf16
// cols). Combine via shfl_xor(16,32). One wave per edge row, 4 rows/block.
__global__ __launch_bounds__(256)
void e_agg_kernel(const float* __restrict__ e, const unsigned* __restrict__ vwb,
                  const int* __restrict__ start, const unsigned* __restrict__ pack,
                  const float* __restrict__ ers, float* __restrict__ eout, int E)
{
    int row = blockIdx.x * 4 + (threadIdx.x >> 6);
    if (row >= E) return;
    int lane = threadIdx.x & 63;
    int qw = lane >> 4;
    int ql = lane & 15;
    int s = start[row], t = start[row + 1];

    float a0=0.f,a1=0.f,a2=0.f,a3=0.f,a4=0.f,a5=0.f,a6=0.f,a7=0.f;
    float b0=0.f,b1=0.f,b2=0.f,b3=0.f,b4=0.f,b5=0.f,b6=0.f,b7=0.f;

    int j = s;
    for (; j + 8 <= t; j += 8) {
        unsigned pw0 = pack[j + qw];
        unsigned pw1 = pack[j + 4 + qw];
        uint4 u0 = *reinterpret_cast<const uint4*>(&vwb[(size_t)(pw0 & 0x1FFFFu) * 64 + ql * 4]);
        uint4 u1 = *reinterpret_cast<const uint4*>(&vwb[(size_t)(pw1 & 0x1FFFFu) * 64 + ql * 4]);
        float w0 = (float)(pw0 >> 17) * (1.0f / 32767.0f);
        float w1 = (float)(pw1 >> 17) * (1.0f / 32767.0f);
        a0 = fmaf(bflo(u0.x), w0, a0); a1 = fmaf(bfhi(u0.x), w0, a1);
        a2 = fmaf(bflo(u0.y), w0, a2); a3 = fmaf(bfhi(u0.y), w0, a3);
        a4 = fmaf(bflo(u0.z), w0, a4); a5 = fmaf(bfhi(u0.z), w0, a5);
        a6 = fmaf(bflo(u0.w), w0, a6); a7 = fmaf(bfhi(u0.w), w0, a7);
        b0 = fmaf(bflo(u1.x), w1, b0); b1 = fmaf(bfhi(u1.x), w1, b1);
        b2 = fmaf(bflo(u1.y), w1, b2); b3 = fmaf(bfhi(u1.y), w1, b3);
        b4 = fmaf(bflo(u1.z), w1, b4); b5 = fmaf(bfhi(u1.z), w1, b5);
        b6 = fmaf(bflo(u1.w), w1, b6); b7 = fmaf(bfhi(u1.w), w1, b7);
    }
    for (; j < t; j += 4) {
        int jj = j + qw;
        if (jj < t) {
            unsigned pw = pack[jj];
            float wm = (float)(pw >> 17) * (1.0f / 32767.0f);
            uint4 u = *reinterpret_cast<const uint4*>(&vwb[(size_t)(pw & 0x1FFFFu) * 64 + ql * 4]);
            a0 = fmaf(bflo(u.x), wm, a0); a1 = fmaf(bfhi(u.x), wm, a1);
            a2 = fmaf(bflo(u.y), wm, a2); a3 = fmaf(bfhi(u.y), wm, a3);
            a4 = fmaf(bflo(u.z), wm, a4); a5 = fmaf(bfhi(u.z), wm, a5);
            a6 = fmaf(bflo(u.w), wm, a6); a7 = fmaf(bfhi(u.w), wm, a7);
        }
    }
    float r0 = a0 + b0, r1 = a1 + b1, r2 = a2 + b2, r3 = a3 + b3;
    float r4 = a4 + b4, r5 = a5 + b5, r6 = a6 + b6, r7 = a7 + b7;
    r0 += __shfl_xor(r0, 16, 64); r0 += __shfl_xor(r0, 32, 64);
    r1 += __shfl_xor(r1, 16, 64); r1 += __shfl_xor(r1, 32, 64);
    r2 += __shfl_xor(r2, 16, 64); r2 += __shfl_xor(r2, 32, 64);
    r3 += __shfl_xor(r3, 16, 64); r3 += __shfl_xor(r3, 32, 64);
    r4 += __shfl_xor(r4, 16, 64); r4 += __shfl_xor(r4, 32, 64);
    r5 += __shfl_xor(r5, 16, 64); r5 += __shfl_xor(r5, 32, 64);
    r6 += __shfl_xor(r6, 16, 64); r6 += __shfl_xor(r6, 32, 64);
    r7 += __shfl_xor(r7, 16, 64); r7 += __shfl_xor(r7, 32, 64);
    if (qw == 0) {
        float rs = 1.0f / ers[row];
        const float4* ep = reinterpret_cast<const float4*>(&e[(size_t)row * DD + ql * 8]);
        float4 e0 = ep[0], e1 = ep[1];
        float4 o0 = make_float4((e0.x + r0) * rs, (e0.y + r1) * rs, (e0.z + r2) * rs, (e0.w + r3) * rs);
        float4 o1 = make_float4((e1.x + r4) * rs, (e1.y + r5) * rs, (e1.z + r6) * rs, (e1.w + r7) * rs);
        float4* op = reinterpret_cast<float4*>(&eout[(size_t)row * DD + ql * 8]);
        op[0] = o0; op[1] = o1;
    }
}

// ---------------------------------------------------------------------------
// v-aggregation, same quarter-wave structure.
__global__ __launch_bounds__(256)
void v_agg_kernel(const float* __restrict__ v, const unsigned* __restrict__ evb,
                  const int* __restrict__ start, const unsigned* __restrict__ pack,
                  const float* __restrict__ vrs, const float* __restrict__ vweight,
                  float* __restrict__ vout, int N)
{
    int row = blockIdx.x * 4 + (threadIdx.x >> 6);
    if (row >= N) return;
    int lane = threadIdx.x & 63;
    int qw = lane >> 4;
    int ql = lane & 15;
    int s = start[row], t = start[row + 1];

    float a0=0.f,a1=0.f,a2=0.f,a3=0.f,a4=0.f,a5=0.f,a6=0.f,a7=0.f;
    float b0=0.f,b1=0.f,b2=0.f,b3=0.f,b4=0.f,b5=0.f,b6=0.f,b7=0.f;

    int j = s;
    for (; j + 8 <= t; j += 8) {
        unsigned pw0 = pack[j + qw];
        unsigned pw1 = pack[j + 4 + qw];
        uint4 u0 = *reinterpret_cast<const uint4*>(&evb[(size_t)(pw0 & 0x1FFFFu) * 64 + ql * 4]);
        uint4 u1 = *reinterpret_cast<const uint4*>(&evb[(size_t)(pw1 & 0x1FFFFu) * 64 + ql * 4]);
        float w0 = (float)(pw0 >> 17) * (1.0f / 32767.0f);
        float w1 = (float)(pw1 >> 17) * (1.0f / 32767.0f);
        a0 = fmaf(bflo(u0.x), w0, a0); a1 = fmaf(bfhi(u0.x), w0, a1);
        a2 = fmaf(bflo(u0.y), w0, a2); a3 = fmaf(bfhi(u0.y), w0, a3);
        a4 = fmaf(bflo(u0.z), w0, a4); a5 = fmaf(bfhi(u0.z), w0, a5);
        a6 = fmaf(bflo(u0.w), w0, a6); a7 = fmaf(bfhi(u0.w), w0, a7);
        b0 = fmaf(bflo(u1.x), w1, b0); b1 = fmaf(bfhi(u1.x), w1, b1);
        b2 = fmaf(bflo(u1.y), w1, b2); b3 = fmaf(bfhi(u1.y), w1, b3);
        b4 = fmaf(bflo(u1.z), w1, b4); b5 = fmaf(bfhi(u1.z), w1, b5);
        b6 = fmaf(bflo(u1.w), w1, b6); b7 = fmaf(bfhi(u1.w), w1, b7);
    }
    for (; j < t; j += 4) {
        int jj = j + qw;
        if (jj < t) {
            unsigned pw = pack[jj];
            float wm = (float)(pw >> 17) * (1.0f / 32767.0f);
            uint4 u = *reinterpret_cast<const uint4*>(&evb[(size_t)(pw & 0x1FFFFu) * 64 + ql * 4]);
            a0 = fmaf(bflo(u.x), wm, a0); a1 = fmaf(bfhi(u.x), wm, a1);
            a2 = fmaf(bflo(u.y), wm, a2); a3 = fmaf(bfhi(u.y), wm, a3);
            a4 = fmaf(bflo(u.z), wm, a4); a5 = fmaf(bfhi(u.z), wm, a5);
            a6 = fmaf(bflo(u.w), wm, a6); a7 = fmaf(bfhi(u.w), wm, a7);
        }
    }
    float r0 = a0 + b0, r1 = a1 + b1, r2 = a2 + b2, r3 = a3 + b3;
    float r4 = a4 + b4, r5 = a5 + b5, r6 = a6 + b6, r7 = a7 + b7;
    r0 += __shfl_xor(r0, 16, 64); r0 += __shfl_xor(r0, 32, 64);
    r1 += __shfl_xor(r1, 16, 64); r1 += __shfl_xor(r1, 32, 64);
    r2 += __shfl_xor(r2, 16, 64); r2 += __shfl_xor(r2, 32, 64);
    r3 += __shfl_xor(r3, 16, 64); r3 += __shfl_xor(r3, 32, 64);
    r4 += __shfl_xor(r4, 16, 64); r4 += __shfl_xor(r4, 32, 64);
    r5 += __shfl_xor(r5, 16, 64); r5 += __shfl_xor(r5, 32, 64);
    r6 += __shfl_xor(r6, 16, 64); r6 += __shfl_xor(r6, 32, 64);
    r7 += __shfl_xor(r7, 16, 64); r7 += __shfl_xor(r7, 32, 64);
    if (qw == 0) {
        float rs = 1.0f / vrs[row];
        float wt = vweight[row] * 4.0f;
        const float4* vp = reinterpret_cast<const float4*>(&v[(size_t)row * DD + ql * 8]);
        float4 v0 = vp[0], v1 = vp[1];
        float4 o0 = make_float4((v0.x * wt + r0) * rs, (v0.y * wt + r1) * rs,
                                (v0.z * wt + r2) * rs, (v0.w * wt + r3) * rs);
        float4 o1 = make_float4((v1.x * wt + r4) * rs, (v1.y * wt + r5) * rs,
                                (v1.z * wt + r6) * rs, (v1.w * wt + r7) * rs);
        float4* op = reinterpret_cast<float4*>(&vout[(size_t)row * DD + ql * 8]);
        op[0] = o0; op[1] = o1;
    }
}

// ---------------------------------------------------------------------------
extern "C" void kernel_launch(void* const* d_in, const int* in_sizes, int n_in,
                              void* d_out, int out_size, void* d_ws, size_t ws_size,
                              hipStream_t stream)
{
    const float* v       = (const float*)d_in[0];
    const float* e       = (const float*)d_in[1];
    const int*   vidx    = (const int*)d_in[2];
    const int*   eidx    = (const int*)d_in[3];
    const float* vrw     = (const float*)d_in[4];
    const float* erw     = (const float*)d_in[5];
    const float* vrs     = (const float*)d_in[6];
    const float* ers     = (const float*)d_in[7];
    const float* Wv2e    = (const float*)d_in[8];
    const float* We2v    = (const float*)d_in[9];
    const float* bv      = (const float*)d_in[10];
    const float* be      = (const float*)d_in[11];
    const float* vweight = (const float*)d_in[12];

    const int N = in_sizes[0] / DD;
    const int E = in_sizes[1] / DD;
    const int M = in_sizes[2];

    float* vout = (float*)d_out;
    float* eout = vout + (size_t)N * DD;

    // bucket geometry
    auto calc_shift = [](int n) {
        int s = 0;
        while (((n + (1 << s) - 1) >> s) > MAXB) ++s;
        return s;
    };
    const int e_shift = calc_shift(E);
    const int v_shift = calc_shift(N);
    const int e_bk = (E + (1 << e_shift) - 1) >> e_shift;
    const int v_bk = (N + (1 << v_shift) - 1) >> v_shift;
    const int e_cap = ((M / e_bk) * 3) / 2 + 256;
    const int v_cap = ((M / v_bk) * 3) / 2 + 256;

    // workspace layout (evb aliases vwb — safe: gemm_e2v runs after e_agg drains)
    char* wsb = (char*)d_ws;
    size_t off = 0;
    auto alloc = [&](size_t bytes) { char* p = wsb + off; off += (bytes + 255) & ~(size_t)255; return p; };
    unsigned* vwb   = (unsigned*)alloc((size_t)N * 64 * sizeof(unsigned));  // 25.6 MB
    unsigned* evb   = vwb;                                                  // alias
    int*   e_start = (int*)alloc((size_t)(E + 1) * sizeof(int));
    int*   v_start = (int*)alloc((size_t)(N + 1) * sizeof(int));
    int*   bcur_e  = (int*)alloc(MAXB * sizeof(int));
    int*   bcur_v  = (int*)alloc(MAXB * sizeof(int));
    unsigned short* Wt0 = (unsigned short*)alloc(DD * DD * sizeof(unsigned short));
    unsigned short* Wt1 = (unsigned short*)alloc(DD * DD * sizeof(unsigned short));
    unsigned* e_pack = (unsigned*)alloc((size_t)M * sizeof(unsigned));      // 4 MB
    unsigned* v_pack = (unsigned*)alloc((size_t)M * sizeof(unsigned));      // 4 MB
    int2*  tmp_e   = (int2*)alloc((size_t)e_bk * e_cap * sizeof(int2));     // ~12.4 MB
    int2*  tmp_v   = (int2*)alloc((size_t)v_bk * v_cap * sizeof(int2));     // ~12.4 MB

    const int pblk = (M + PART_ELEMS - 1) / PART_ELEMS;
    const int gblkN = (N + 63) / 64;

    // 0. zero delta cursors (async, 2 KB)
    hipMemsetAsync(bcur_e, 0, MAXB * sizeof(int), stream);
    hipMemsetAsync(bcur_v, 0, MAXB * sizeof(int), stream);
    // 1. W convert
    conv_w_kernel<<<64, 256, 0, stream>>>(Wv2e, We2v, Wt0, Wt1);
    // 2. fused both-sides partition
    part2_kernel<<<pblk, 256, 0, stream>>>(eidx, vidx, vrw, erw, bcur_e, bcur_v,
                                           tmp_e, tmp_v, M, e_shift, v_shift, e_bk, v_bk,
                                           e_cap, v_cap);
    // 3. fused fine pass + v2e GEMM
    fused_fine_gemm_kernel<<<e_bk + v_bk + gblkN, 256, 0, stream>>>(
        tmp_e, bcur_e, e_cap, e_shift, E, e_bk, e_start, e_pack,
        tmp_v, bcur_v, v_cap, v_shift, N, v_bk, v_start, v_pack, M,
        v, Wt0, bv, vweight, vwb);
    // 4. e-aggregation
    e_agg_kernel<<<(E + 3) / 4, 256, 0, stream>>>(e, vwb, e_start, e_pack, ers, eout, E);
    // 5. e2v GEMM
    gemm_mfma_kernel<<<(E + 63) / 64, 256, 0, stream>>>(eout, Wt1, be, evb, E, 1.0f / 3.0f);
    // 6. v-aggregation
    v_agg_kernel<<<(N + 3) / 4, 256, 0, stream>>>(v, evb, v_start, v_pack, vrs, vweight, vout, N);
}

// Round 17
// 182.004 us; speedup vs baseline: 1.1281x; 1.1281x over previous
//
#include <hip/hip_runtime.h>
#include <cstddef>

#define DD 128
#define PART_ELEMS 4096   // elements per partition block (256 thr x 16)
#define MAXB 256          // max destination-range buckets
#define MAXW 512          // max rows per bucket (LDS counter width)
#define WT_LD 136         // padded bf16 leading dim

typedef __attribute__((ext_vector_type(8))) short bf16x8;
typedef __attribute__((ext_vector_type(4))) float f32x4;

__device__ __forceinline__ unsigned bf16pk(float x, float y) {
    unsigned a = __float_as_uint(x);
    unsigned b = __float_as_uint(y);
    a = (a + 0x7FFFu + ((a >> 16) & 1u)) >> 16;
    b = (b + 0x7FFFu + ((b >> 16) & 1u)) >> 16;
    return a | (b << 16);
}
__device__ __forceinline__ unsigned short bf16r(float x) {
    unsigned u = __float_as_uint(x);
    return (unsigned short)((u + 0x7FFFu + ((u >> 16) & 1u)) >> 16);
}
__device__ __forceinline__ float bflo(unsigned u) { return __uint_as_float(u << 16); }
__device__ __forceinline__ float bfhi(unsigned u) { return __uint_as_float(u & 0xFFFF0000u); }

// ---------------------------------------------------------------------------
// one-time: W [k][col] f32 -> Wt [col][k] bf16 (two matrices) + bucket cursor init
__global__ __launch_bounds__(256)
void conv_w_kernel(const float* __restrict__ W0, const float* __restrict__ W1,
                   unsigned short* __restrict__ Wt0, unsigned short* __restrict__ Wt1,
                   int* __restrict__ bcur_e, int* __restrict__ bcur_v, int e_cap, int v_cap)
{
    int idx = blockIdx.x * 256 + threadIdx.x;
    int k = idx >> 7, c = idx & 127;
    Wt0[c * 128 + k] = bf16r(W0[idx]);
    Wt1[c * 128 + k] = bf16r(W1[idx]);
    if (blockIdx.x == 0) {
        bcur_e[threadIdx.x] = threadIdx.x * e_cap;
        bcur_v[threadIdx.x] = threadIdx.x * v_cap;
    }
}

// ---------------------------------------------------------------------------
// fused partition: both sides in one pass over the incidence list.
__global__ __launch_bounds__(256)
void part2_kernel(const int* __restrict__ eidx, const int* __restrict__ vidx,
                  const float* __restrict__ vrw, const float* __restrict__ erw,
                  int* __restrict__ bcur_e, int* __restrict__ bcur_v,
                  int2* __restrict__ tmp_e, int2* __restrict__ tmp_v,
                  int M, int e_shift, int v_shift, int e_bk, int v_bk)
{
    __shared__ int lcnt_e[MAXB], lbase_e[MAXB], lcnt_v[MAXB], lbase_v[MAXB];
    const int t = threadIdx.x;
    const int base = blockIdx.x * PART_ELEMS;
    const int end = min(base + PART_ELEMS, M);

    if (t < e_bk) lcnt_e[t] = 0;
    if (t < v_bk) lcnt_v[t] = 0;
    __syncthreads();
    for (int j = base + t; j < end; j += 256) {
        atomicAdd(&lcnt_e[eidx[j] >> e_shift], 1);
        atomicAdd(&lcnt_v[vidx[j] >> v_shift], 1);
    }
    __syncthreads();
    if (t < e_bk) { int c = lcnt_e[t]; lbase_e[t] = c ? atomicAdd(&bcur_e[t], c) : 0; lcnt_e[t] = 0; }
    if (t < v_bk) { int c = lcnt_v[t]; lbase_v[t] = c ? atomicAdd(&bcur_v[t], c) : 0; lcnt_v[t] = 0; }
    __syncthreads();
    for (int j = base + t; j < end; j += 256) {
        int ei = eidx[j], vi = vidx[j];
        int wqe = (int)(vrw[j] * 32767.0f + 0.5f); wqe = wqe < 32767 ? wqe : 32767;
        int wqv = (int)(erw[j] * 32767.0f + 0.5f); wqv = wqv < 32767 ? wqv : 32767;
        int be = ei >> e_shift;
        int pe = lbase_e[be] + atomicAdd(&lcnt_e[be], 1);
        tmp_e[pe] = make_int2(ei | (wqe << 17), vi);
        int bv = vi >> v_shift;
        int pv = lbase_v[bv] + atomicAdd(&lcnt_v[bv], 1);
        tmp_v[pv] = make_int2(vi | (wqv << 17), ei);
    }
}

// ---------------------------------------------------------------------------
// device bodies so fine-pass and GEMM can share one fused launch
struct FineLds { int lcnt[MAXW]; int lstart[MAXW]; int sdata[256]; int scnt[256]; int spbase; };
struct GemmLds { unsigned short Wt[128 * WT_LD]; unsigned short At[64 * WT_LD]; };

__device__ __forceinline__
void fine_body(int blk, FineLds& L,
               const int2* __restrict__ tmp_e, const int* __restrict__ bcur_e,
               int e_cap, int e_shift, int En, int e_bk,
               int* __restrict__ e_start, unsigned* __restrict__ e_pack,
               const int2* __restrict__ tmp_v, const int* __restrict__ bcur_v,
               int v_cap, int v_shift, int Nn, int v_bk,
               int* __restrict__ v_start, unsigned* __restrict__ v_pack, int M)
{
    const int t = threadIdx.x;
    const int2* tmp; const int* bcur; int cap, shift, n, nb, b;
    int* start; unsigned* pack;
    if (blk < e_bk) {
        tmp = tmp_e; bcur = bcur_e; cap = e_cap; shift = e_shift; n = En; nb = e_bk;
        start = e_start; pack = e_pack; b = blk;
    } else {
        tmp = tmp_v; bcur = bcur_v; cap = v_cap; shift = v_shift; n = Nn; nb = v_bk;
        start = v_start; pack = v_pack; b = blk - e_bk;
    }

    // self-computed pack base: exclusive prefix of bucket counts up to b
    int cnt_t = (t < nb) ? (bcur[t] - t * cap) : 0;
    L.scnt[t] = cnt_t;
    __syncthreads();
    int xx = cnt_t;
    for (int off = 1; off < 256; off <<= 1) {
        int y = (t >= off) ? L.scnt[t - off] : 0;
        __syncthreads();
        xx += y;
        L.scnt[t] = xx;
        __syncthreads();
    }
    if (t == b) L.spbase = xx - cnt_t;
    if (b == nb - 1 && t == 0) start[n] = M;
    __syncthreads();
    const int pbase = L.spbase;

    const int d0 = b << shift;
    const int width = min(1 << shift, n - d0);
    const int tbase = b * cap;
    const int nrec = bcur[b] - tbase;

    L.lcnt[t] = 0; L.lcnt[t + 256] = 0;
    __syncthreads();
    for (int j = t; j < nrec; j += 256)
        atomicAdd(&L.lcnt[(tmp[tbase + j].x & 0x1FFFF) - d0], 1);
    __syncthreads();
    int a = L.lcnt[2 * t], bb = L.lcnt[2 * t + 1];
    int s = a + bb;
    L.sdata[t] = s;
    __syncthreads();
    int x = s;
    for (int off = 1; off < 256; off <<= 1) {
        int y = (t >= off) ? L.sdata[t - off] : 0;
        __syncthreads();
        x += y;
        L.sdata[t] = x;
        __syncthreads();
    }
    int ex = x - s;
    L.lstart[2 * t] = ex;
    L.lstart[2 * t + 1] = ex + a;
    L.lcnt[2 * t] = 0; L.lcnt[2 * t + 1] = 0;   // reuse as cursors
    __syncthreads();
    for (int i = t; i < width; i += 256)
        start[d0 + i] = pbase + L.lstart[i];
    for (int j = t; j < nrec; j += 256) {
        int2 r = tmp[tbase + j];
        int di = (r.x & 0x1FFFF) - d0;
        int pos = pbase + L.lstart[di] + atomicAdd(&L.lcnt[di], 1);
        pack[pos] = (unsigned)r.y | (((unsigned)r.x >> 17) << 17);
    }
}

__device__ __forceinline__
void gemm_body(int blk, GemmLds& L, const float* __restrict__ A,
               const unsigned short* __restrict__ Wtg, const float* __restrict__ bias,
               const float* __restrict__ rowwt, unsigned* __restrict__ outb,
               int nrows, float scale, bool v2e)
{
    const int t = threadIdx.x;
    const int row0 = blk * 64;

    {
        int r = t >> 1, h = t & 1;
        const uint4* src = reinterpret_cast<const uint4*>(Wtg + r * 128 + h * 64);
        uint4* dst = reinterpret_cast<uint4*>(&L.Wt[r * WT_LD + h * 64]);
        #pragma unroll
        for (int i = 0; i < 8; ++i) dst[i] = src[i];
    }
    {
        int r = t >> 2, q = t & 3;
        int grow = row0 + r;
        uint4 o[4];
        if (grow < nrows) {
            const float4* src = reinterpret_cast<const float4*>(A + (size_t)grow * DD + q * 32);
            #pragma unroll
            for (int i = 0; i < 4; ++i) {
                float4 f0 = src[2 * i];
                float4 f1 = src[2 * i + 1];
                o[i].x = bf16pk(f0.x, f0.y);
                o[i].y = bf16pk(f0.z, f0.w);
                o[i].z = bf16pk(f1.x, f1.y);
                o[i].w = bf16pk(f1.z, f1.w);
            }
        } else {
            #pragma unroll
            for (int i = 0; i < 4; ++i) o[i] = make_uint4(0, 0, 0, 0);
        }
        uint4* dst = reinterpret_cast<uint4*>(&L.At[r * WT_LD + q * 32]);
        #pragma unroll
        for (int i = 0; i < 4; ++i) dst[i] = o[i];
    }
    __syncthreads();

    const int w  = t >> 6;
    const int l  = t & 63;
    const int lr = l & 15;
    const int lk = (l >> 4) * 8;

    f32x4 acc[8];
    #pragma unroll
    for (int i = 0; i < 8; ++i) acc[i] = 0.0f;

    const int arow = w * 16 + lr;
    #pragma unroll
    for (int ks = 0; ks < 4; ++ks) {
        bf16x8 af = *reinterpret_cast<const bf16x8*>(&L.At[arow * WT_LD + lk + ks * 32]);
        #pragma unroll
        for (int ct = 0; ct < 8; ++ct) {
            bf16x8 bfr = *reinterpret_cast<const bf16x8*>(&L.Wt[(ct * 16 + lr) * WT_LD + lk + ks * 32]);
            acc[ct] = __builtin_amdgcn_mfma_f32_16x16x32_bf16(af, bfr, acc[ct], 0, 0, 0);
        }
    }

    float bcol[8];
    #pragma unroll
    for (int ct = 0; ct < 8; ++ct) bcol[ct] = bias[ct * 16 + lr];
    #pragma unroll
    for (int r = 0; r < 4; ++r) {
        int rl = w * 16 + (l >> 4) * 4 + r;
        int grow = row0 + rl;
        float rw = scale;
        if (v2e) rw = (grow < nrows) ? rowwt[grow] : 0.f;
        #pragma unroll
        for (int ct = 0; ct < 8; ++ct) {
            float val = fmaxf(acc[ct][r] + bcol[ct], 0.f) * rw;
            L.At[rl * WT_LD + ct * 16 + lr] = bf16r(val);
        }
    }
    {
        int r = t >> 2, part = t & 3;
        int grow = row0 + r;
        if (grow < nrows) {
            const uint4* src = reinterpret_cast<const uint4*>(&L.At[r * WT_LD + part * 32]);
            uint4* dst = reinterpret_cast<uint4*>(outb + (size_t)grow * 64 + part * 16);
            dst[0] = src[0]; dst[1] = src[1]; dst[2] = src[2]; dst[3] = src[3];
        }
    }
}

// ---------------------------------------------------------------------------
// fused launch: blocks [0, e_bk+v_bk) do the fine pass; the rest do the v2e GEMM
__global__ __launch_bounds__(256)
void fused_fine_gemm_kernel(const int2* __restrict__ tmp_e, const int* __restrict__ bcur_e,
                            int e_cap, int e_shift, int En, int e_bk,
                            int* __restrict__ e_start, unsigned* __restrict__ e_pack,
                            const int2* __restrict__ tmp_v, const int* __restrict__ bcur_v,
                            int v_cap, int v_shift, int Nn, int v_bk,
                            int* __restrict__ v_start, unsigned* __restrict__ v_pack, int M,
                            const float* __restrict__ v, const unsigned short* __restrict__ Wt0,
                            const float* __restrict__ bv, const float* __restrict__ vweight,
                            unsigned* __restrict__ vwb)
{
    __shared__ union SM { FineLds f; GemmLds g; } sm;
    const int nfine = e_bk + v_bk;
    if ((int)blockIdx.x < nfine) {
        fine_body(blockIdx.x, sm.f, tmp_e, bcur_e, e_cap, e_shift, En, e_bk, e_start, e_pack,
                  tmp_v, bcur_v, v_cap, v_shift, Nn, v_bk, v_start, v_pack, M);
    } else {
        gemm_body(blockIdx.x - nfine, sm.g, v, Wt0, bv, vweight, vwb, Nn, 1.0f, true);
    }
}

// standalone GEMM for the e2v side
__global__ __launch_bounds__(256)
void gemm_mfma_kernel(const float* __restrict__ A, const unsigned short* __restrict__ Wtg,
                      const float* __restrict__ bias, unsigned* __restrict__ outb,
                      int nrows, float scale)
{
    __shared__ GemmLds sm;
    gemm_body(blockIdx.x, sm, A, Wtg, bias, nullptr, outb, nrows, scale, false);
}

// ---------------------------------------------------------------------------
// e-aggregation, quarter-wave gathers: lane group (lane>>4) takes incidence
// j+qw; each lane loads uint4 (8 bf16 cols). Combine via shfl_xor(16,32).
__global__ __launch_bounds__(256)
void e_agg_kernel(const float* __restrict__ e, const unsigned* __restrict__ vwb,
                  const int* __restrict__ start, const unsigned* __restrict__ pack,
                  const float* __restrict__ ers, float* __restrict__ eout, int E)
{
    int row = blockIdx.x * 4 + (threadIdx.x >> 6);
    if (row >= E) return;
    int lane = threadIdx.x & 63;
    int qw = lane >> 4;
    int ql = lane & 15;
    int s = start[row], t = start[row + 1];

    float a0=0.f,a1=0.f,a2=0.f,a3=0.f,a4=0.f,a5=0.f,a6=0.f,a7=0.f;
    float b0=0.f,b1=0.f,b2=0.f,b3=0.f,b4=0.f,b5=0.f,b6=0.f,b7=0.f;

    int j = s;
    for (; j + 8 <= t; j += 8) {
        unsigned pw0 = pack[j + qw];
        unsigned pw1 = pack[j + 4 + qw];
        uint4 u0 = *reinterpret_cast<const uint4*>(&vwb[(size_t)(pw0 & 0x1FFFFu) * 64 + ql * 4]);
        uint4 u1 = *reinterpret_cast<const uint4*>(&vwb[(size_t)(pw1 & 0x1FFFFu) * 64 + ql * 4]);
        float w0 = (float)(pw0 >> 17) * (1.0f / 32767.0f);
        float w1 = (float)(pw1 >> 17) * (1.0f / 32767.0f);
        a0 = fmaf(bflo(u0.x), w0, a0); a1 = fmaf(bfhi(u0.x), w0, a1);
        a2 = fmaf(bflo(u0.y), w0, a2); a3 = fmaf(bfhi(u0.y), w0, a3);
        a4 = fmaf(bflo(u0.z), w0, a4); a5 = fmaf(bfhi(u0.z), w0, a5);
        a6 = fmaf(bflo(u0.w), w0, a6); a7 = fmaf(bfhi(u0.w), w0, a7);
        b0 = fmaf(bflo(u1.x), w1, b0); b1 = fmaf(bfhi(u1.x), w1, b1);
        b2 = fmaf(bflo(u1.y), w1, b2); b3 = fmaf(bfhi(u1.y), w1, b3);
        b4 = fmaf(bflo(u1.z), w1, b4); b5 = fmaf(bfhi(u1.z), w1, b5);
        b6 = fmaf(bflo(u1.w), w1, b6); b7 = fmaf(bfhi(u1.w), w1, b7);
    }
    for (; j < t; j += 4) {
        int jj = j + qw;
        if (jj < t) {
            unsigned pw = pack[jj];
            float wm = (float)(pw >> 17) * (1.0f / 32767.0f);
            uint4 u = *reinterpret_cast<const uint4*>(&vwb[(size_t)(pw & 0x1FFFFu) * 64 + ql * 4]);
            a0 = fmaf(bflo(u.x), wm, a0); a1 = fmaf(bfhi(u.x), wm, a1);
            a2 = fmaf(bflo(u.y), wm, a2); a3 = fmaf(bfhi(u.y), wm, a3);
            a4 = fmaf(bflo(u.z), wm, a4); a5 = fmaf(bfhi(u.z), wm, a5);
            a6 = fmaf(bflo(u.w), wm, a6); a7 = fmaf(bfhi(u.w), wm, a7);
        }
    }
    float r0 = a0 + b0, r1 = a1 + b1, r2 = a2 + b2, r3 = a3 + b3;
    float r4 = a4 + b4, r5 = a5 + b5, r6 = a6 + b6, r7 = a7 + b7;
    r0 += __shfl_xor(r0, 16, 64); r0 += __shfl_xor(r0, 32, 64);
    r1 += __shfl_xor(r1, 16, 64); r1 += __shfl_xor(r1, 32, 64);
    r2 += __shfl_xor(r2, 16, 64); r2 += __shfl_xor(r2, 32, 64);
    r3 += __shfl_xor(r3, 16, 64); r3 += __shfl_xor(r3, 32, 64);
    r4 += __shfl_xor(r4, 16, 64); r4 += __shfl_xor(r4, 32, 64);
    r5 += __shfl_xor(r5, 16, 64); r5 += __shfl_xor(r5, 32, 64);
    r6 += __shfl_xor(r6, 16, 64); r6 += __shfl_xor(r6, 32, 64);
    r7 += __shfl_xor(r7, 16, 64); r7 += __shfl_xor(r7, 32, 64);
    if (qw == 0) {
        float rs = 1.0f / ers[row];
        const float4* ep = reinterpret_cast<const float4*>(&e[(size_t)row * DD + ql * 8]);
        float4 e0 = ep[0], e1 = ep[1];
        float4 o0 = make_float4((e0.x + r0) * rs, (e0.y + r1) * rs, (e0.z + r2) * rs, (e0.w + r3) * rs);
        float4 o1 = make_float4((e1.x + r4) * rs, (e1.y + r5) * rs, (e1.z + r6) * rs, (e1.w + r7) * rs);
        float4* op = reinterpret_cast<float4*>(&eout[(size_t)row * DD + ql * 8]);
        op[0] = o0; op[1] = o1;
    }
}

// ---------------------------------------------------------------------------
// v-aggregation, same quarter-wave structure.
__global__ __launch_bounds__(256)
void v_agg_kernel(const float* __restrict__ v, const unsigned* __restrict__ evb,
                  const int* __restrict__ start, const unsigned* __restrict__ pack,
                  const float* __restrict__ vrs, const float* __restrict__ vweight,
                  float* __restrict__ vout, int N)
{
    int row = blockIdx.x * 4 + (threadIdx.x >> 6);
    if (row >= N) return;
    int lane = threadIdx.x & 63;
    int qw = lane >> 4;
    int ql = lane & 15;
    int s = start[row], t = start[row + 1];

    float a0=0.f,a1=0.f,a2=0.f,a3=0.f,a4=0.f,a5=0.f,a6=0.f,a7=0.f;
    float b0=0.f,b1=0.f,b2=0.f,b3=0.f,b4=0.f,b5=0.f,b6=0.f,b7=0.f;

    int j = s;
    for (; j + 8 <= t; j += 8) {
        unsigned pw0 = pack[j + qw];
        unsigned pw1 = pack[j + 4 + qw];
        uint4 u0 = *reinterpret_cast<const uint4*>(&evb[(size_t)(pw0 & 0x1FFFFu) * 64 + ql * 4]);
        uint4 u1 = *reinterpret_cast<const uint4*>(&evb[(size_t)(pw1 & 0x1FFFFu) * 64 + ql * 4]);
        float w0 = (float)(pw0 >> 17) * (1.0f / 32767.0f);
        float w1 = (float)(pw1 >> 17) * (1.0f / 32767.0f);
        a0 = fmaf(bflo(u0.x), w0, a0); a1 = fmaf(bfhi(u0.x), w0, a1);
        a2 = fmaf(bflo(u0.y), w0, a2); a3 = fmaf(bfhi(u0.y), w0, a3);
        a4 = fmaf(bflo(u0.z), w0, a4); a5 = fmaf(bfhi(u0.z), w0, a5);
        a6 = fmaf(bflo(u0.w), w0, a6); a7 = fmaf(bfhi(u0.w), w0, a7);
        b0 = fmaf(bflo(u1.x), w1, b0); b1 = fmaf(bfhi(u1.x), w1, b1);
        b2 = fmaf(bflo(u1.y), w1, b2); b3 = fmaf(bfhi(u1.y), w1, b3);
        b4 = fmaf(bflo(u1.z), w1, b4); b5 = fmaf(bfhi(u1.z), w1, b5);
        b6 = fmaf(bflo(u1.w), w1, b6); b7 = fmaf(bfhi(u1.w), w1, b7);
    }
    for (; j < t; j += 4) {
        int jj = j + qw;
        if (jj < t) {
            unsigned pw = pack[jj];
            float wm = (float)(pw >> 17) * (1.0f / 32767.0f);
            uint4 u = *reinterpret_cast<const uint4*>(&evb[(size_t)(pw & 0x1FFFFu) * 64 + ql * 4]);
            a0 = fmaf(bflo(u.x), wm, a0); a1 = fmaf(bfhi(u.x), wm, a1);
            a2 = fmaf(bflo(u.y), wm, a2); a3 = fmaf(bfhi(u.y), wm, a3);
            a4 = fmaf(bflo(u.z), wm, a4); a5 = fmaf(bfhi(u.z), wm, a5);
            a6 = fmaf(bflo(u.w), wm, a6); a7 = fmaf(bfhi(u.w), wm, a7);
        }
    }
    float r0 = a0 + b0, r1 = a1 + b1, r2 = a2 + b2, r3 = a3 + b3;
    float r4 = a4 + b4, r5 = a5 + b5, r6 = a6 + b6, r7 = a7 + b7;
    r0 += __shfl_xor(r0, 16, 64); r0 += __shfl_xor(r0, 32, 64);
    r1 += __shfl_xor(r1, 16, 64); r1 += __shfl_xor(r1, 32, 64);
    r2 += __shfl_xor(r2, 16, 64); r2 += __shfl_xor(r2, 32, 64);
    r3 += __shfl_xor(r3, 16, 64); r3 += __shfl_xor(r3, 32, 64);
    r4 += __shfl_xor(r4, 16, 64); r4 += __shfl_xor(r4, 32, 64);
    r5 += __shfl_xor(r5, 16, 64); r5 += __shfl_xor(r5, 32, 64);
    r6 += __shfl_xor(r6, 16, 64); r6 += __shfl_xor(r6, 32, 64);
    r7 += __shfl_xor(r7, 16, 64); r7 += __shfl_xor(r7, 32, 64);
    if (qw == 0) {
        float rs = 1.0f / vrs[row];
        float wt = vweight[row] * 4.0f;
        const float4* vp = reinterpret_cast<const float4*>(&v[(size_t)row * DD + ql * 8]);
        float4 v0 = vp[0], v1 = vp[1];
        float4 o0 = make_float4((v0.x * wt + r0) * rs, (v0.y * wt + r1) * rs,
                                (v0.z * wt + r2) * rs, (v0.w * wt + r3) * rs);
        float4 o1 = make_float4((v1.x * wt + r4) * rs, (v1.y * wt + r5) * rs,
                                (v1.z * wt + r6) * rs, (v1.w * wt + r7) * rs);
        float4* op = reinterpret_cast<float4*>(&vout[(size_t)row * DD + ql * 8]);
        op[0] = o0; op[1] = o1;
    }
}

// ---------------------------------------------------------------------------
extern "C" void kernel_launch(void* const* d_in, const int* in_sizes, int n_in,
                              void* d_out, int out_size, void* d_ws, size_t ws_size,
                              hipStream_t stream)
{
    const float* v       = (const float*)d_in[0];
    const float* e       = (const float*)d_in[1];
    const int*   vidx    = (const int*)d_in[2];
    const int*   eidx    = (const int*)d_in[3];
    const float* vrw     = (const float*)d_in[4];
    const float* erw     = (const float*)d_in[5];
    const float* vrs     = (const float*)d_in[6];
    const float* ers     = (const float*)d_in[7];
    const float* Wv2e    = (const float*)d_in[8];
    const float* We2v    = (const float*)d_in[9];
    const float* bv      = (const float*)d_in[10];
    const float* be      = (const float*)d_in[11];
    const float* vweight = (const float*)d_in[12];

    const int N = in_sizes[0] / DD;
    const int E = in_sizes[1] / DD;
    const int M = in_sizes[2];

    float* vout = (float*)d_out;
    float* eout = vout + (size_t)N * DD;

    // bucket geometry
    auto calc_shift = [](int n) {
        int s = 0;
        while (((n + (1 << s) - 1) >> s) > MAXB) ++s;
        return s;
    };
    const int e_shift = calc_shift(E);
    const int v_shift = calc_shift(N);
    const int e_bk = (E + (1 << e_shift) - 1) >> e_shift;
    const int v_bk = (N + (1 << v_shift) - 1) >> v_shift;
    const int e_cap = ((M / e_bk) * 3) / 2 + 256;
    const int v_cap = ((M / v_bk) * 3) / 2 + 256;

    // workspace layout (evb aliases vwb)
    char* wsb = (char*)d_ws;
    size_t off = 0;
    auto alloc = [&](size_t bytes) { char* p = wsb + off; off += (bytes + 255) & ~(size_t)255; return p; };
    unsigned* vwb   = (unsigned*)alloc((size_t)N * 64 * sizeof(unsigned));  // 25.6 MB
    unsigned* evb   = vwb;                                                  // alias
    int*   e_start = (int*)alloc((size_t)(E + 1) * sizeof(int));
    int*   v_start = (int*)alloc((size_t)(N + 1) * sizeof(int));
    int*   bcur_e  = (int*)alloc(MAXB * sizeof(int));
    int*   bcur_v  = (int*)alloc(MAXB * sizeof(int));
    unsigned short* Wt0 = (unsigned short*)alloc(DD * DD * sizeof(unsigned short));
    unsigned short* Wt1 = (unsigned short*)alloc(DD * DD * sizeof(unsigned short));
    unsigned* e_pack = (unsigned*)alloc((size_t)M * sizeof(unsigned));      // 4 MB
    unsigned* v_pack = (unsigned*)alloc((size_t)M * sizeof(unsigned));      // 4 MB
    int2*  tmp_e   = (int2*)alloc((size_t)e_bk * e_cap * sizeof(int2));     // ~12.4 MB
    int2*  tmp_v   = (int2*)alloc((size_t)v_bk * v_cap * sizeof(int2));     // ~12.4 MB

    const int pblk = (M + PART_ELEMS - 1) / PART_ELEMS;
    const int gblkN = (N + 63) / 64;

    // 1. W convert + bucket cursor init
    conv_w_kernel<<<64, 256, 0, stream>>>(Wv2e, We2v, Wt0, Wt1, bcur_e, bcur_v, e_cap, v_cap);
    // 2. fused both-sides partition
    part2_kernel<<<pblk, 256, 0, stream>>>(eidx, vidx, vrw, erw, bcur_e, bcur_v,
                                           tmp_e, tmp_v, M, e_shift, v_shift, e_bk, v_bk);
    // 3. fused fine pass + v2e GEMM (independent of each other)
    fused_fine_gemm_kernel<<<e_bk + v_bk + gblkN, 256, 0, stream>>>(
        tmp_e, bcur_e, e_cap, e_shift, E, e_bk, e_start, e_pack,
        tmp_v, bcur_v, v_cap, v_shift, N, v_bk, v_start, v_pack, M,
        v, Wt0, bv, vweight, vwb);
    // 4. e-aggregation
    e_agg_kernel<<<(E + 3) / 4, 256, 0, stream>>>(e, vwb, e_start, e_pack, ers, eout, E);
    // 5. e2v GEMM
    gemm_mfma_kernel<<<(E + 63) / 64, 256, 0, stream>>>(eout, Wt1, be, evb, E, 1.0f / 3.0f);
    // 6. v-aggregation
    v_agg_kernel<<<(N + 3) / 4, 256, 0, stream>>>(v, evb, v_start, v_pack, vrs, vweight, vout, N);
}